// Round 8
// baseline (122.556 us; speedup 1.0000x reference)
//
#include <hip/hip_runtime.h>

#define FFT_N 1024
#define NBLK2 2048      // 4 waves/block x 2 rows/wave -> 8 rows/block, 16384 rows

typedef float float4n __attribute__((ext_vector_type(4)));

__device__ __forceinline__ int br6(int x) { return (int)(__brev((unsigned)x) >> 26); }

__device__ __forceinline__ unsigned int f2key(float f) {
    unsigned int u = __float_as_uint(f);
    return (u & 0x80000000u) ? ~u : (u | 0x80000000u);
}
__device__ __forceinline__ float key2f(unsigned int k) {
    unsigned int u = (k & 0x80000000u) ? (k & 0x7FFFFFFFu) : ~k;
    return __uint_as_float(u);
}

__global__ void init_mm(unsigned int* mm) {
    mm[0] = 0xFFFFFFFFu;
    mm[1] = 0u;
}

// ---- helpers for the Hermitian-packed 512-pt inverse FFT (see R6 derivation) ----

// in-register 8-pt inverse DIF over reg index (natural in, bit-rev out)
__device__ __forceinline__ void dif8(float* Zr, float* Zi) {
    const float R = 0.70710678118654752f;
    float tr, ti;
    tr = Zr[0]-Zr[4]; ti = Zi[0]-Zi[4]; Zr[0]+=Zr[4]; Zi[0]+=Zi[4]; Zr[4]=tr;        Zi[4]=ti;
    tr = Zr[1]-Zr[5]; ti = Zi[1]-Zi[5]; Zr[1]+=Zr[5]; Zi[1]+=Zi[5]; Zr[5]=R*(tr-ti); Zi[5]=R*(tr+ti);
    tr = Zr[2]-Zr[6]; ti = Zi[2]-Zi[6]; Zr[2]+=Zr[6]; Zi[2]+=Zi[6]; Zr[6]=-ti;       Zi[6]=tr;
    tr = Zr[3]-Zr[7]; ti = Zi[3]-Zi[7]; Zr[3]+=Zr[7]; Zi[3]+=Zi[7]; Zr[7]=-R*(tr+ti);Zi[7]=R*(tr-ti);
    tr = Zr[0]-Zr[2]; ti = Zi[0]-Zi[2]; Zr[0]+=Zr[2]; Zi[0]+=Zi[2]; Zr[2]=tr;  Zi[2]=ti;
    tr = Zr[1]-Zr[3]; ti = Zi[1]-Zi[3]; Zr[1]+=Zr[3]; Zi[1]+=Zi[3]; Zr[3]=-ti; Zi[3]=tr;
    tr = Zr[4]-Zr[6]; ti = Zi[4]-Zi[6]; Zr[4]+=Zr[6]; Zi[4]+=Zi[6]; Zr[6]=tr;  Zi[6]=ti;
    tr = Zr[5]-Zr[7]; ti = Zi[5]-Zi[7]; Zr[5]+=Zr[7]; Zi[5]+=Zi[7]; Zr[7]=-ti; Zi[7]=tr;
    tr = Zr[0]-Zr[1]; ti = Zi[0]-Zi[1]; Zr[0]+=Zr[1]; Zi[0]+=Zi[1]; Zr[1]=tr; Zi[1]=ti;
    tr = Zr[2]-Zr[3]; ti = Zi[2]-Zi[3]; Zr[2]+=Zr[3]; Zi[2]+=Zi[3]; Zr[3]=tr; Zi[3]=ti;
    tr = Zr[4]-Zr[5]; ti = Zi[4]-Zi[5]; Zr[4]+=Zr[5]; Zi[4]+=Zi[5]; Zr[5]=tr; Zi[5]=ti;
    tr = Zr[6]-Zr[7]; ti = Zi[6]-Zi[7]; Zr[6]+=Zr[7]; Zi[6]+=Zi[7]; Zr[7]=tr; Zi[7]=ti;
}

__device__ __constant__ int BR3[8] = {0, 4, 2, 6, 1, 5, 3, 7};

// Two independent rows per wave, phases interleaved for ILP/MLP.
template <bool USE_ATOMIC>
__global__ __launch_bounds__(256, 3) void zifft_rows2(const float* __restrict__ x,
                                                      float* __restrict__ out,
                                                      float* __restrict__ partials,
                                                      unsigned int* __restrict__ mm) {
    const int t    = threadIdx.x;
    const int lane = t & 63;
    const int wid  = t >> 6;
    const int pair = blockIdx.x * 4 + wid;   // 0 .. 8191
    const int rowA = pair * 2;
    const int rowB = rowA + 1;               // same batch (rows/batch = 1024, even)
    const int b    = rowA >> 10;
    const int pA   = rowA & 1023;
    const float* reA = x + (((size_t)(b * 2)) * 1024 + pA) * 1024;
    const float* imA = reA + (size_t)1024 * 1024;
    const float* reB = reA + 1024;
    const float* imB = imA + 1024;

    // ---- issue ALL loads for both rows first (max loads in flight) ----
    float uAr[8], uAi[8], pAr[8], pAi[8], qAr[8], qAi[8], vAr[8], vAi[8];
    float uBr[8], uBi[8], pBr[8], pBi[8], qBr[8], qBi[8], vBr[8], vBi[8];
    #pragma unroll
    for (int j = 0; j < 8; ++j) {
        const int k  = lane + 64 * j;
        const int iq = 512 - k;
        const int iv = (1024 - k) & 1023;
        uAr[j] = reA[k];       uAi[j] = imA[k];
        pAr[j] = reA[k + 512]; pAi[j] = imA[k + 512];
        qAr[j] = reA[iq];      qAi[j] = imA[iq];
        vAr[j] = reA[iv];      vAi[j] = imA[iv];
    }
    #pragma unroll
    for (int j = 0; j < 8; ++j) {
        const int k  = lane + 64 * j;
        const int iq = 512 - k;
        const int iv = (1024 - k) & 1023;
        uBr[j] = reB[k];       uBi[j] = imB[k];
        pBr[j] = reB[k + 512]; pBi[j] = imB[k + 512];
        qBr[j] = reB[iq];      qBi[j] = imB[iq];
        vBr[j] = reB[iv];      vBi[j] = imB[iv];
    }

    // ---- pack: Z'[k] = A' + i*W^k*B', W^k = e^{+2pi i k/1024} (both rows) ----
    float ZAr[8], ZAi[8], ZBr[8], ZBi[8];
    #pragma unroll
    for (int j = 0; j < 8; ++j) {
        const int k = lane + 64 * j;
        float s, c;
        __sincosf(6.135923151542565e-3f * (float)k, &s, &c);   // 2pi*k/1024
        {
            float Ar = pAr[j] + uAr[j] + qAr[j] + vAr[j];
            float Ai = pAi[j] + uAi[j] - qAi[j] - vAi[j];
            float Br = pAr[j] - uAr[j] + qAr[j] - vAr[j];
            float Bi = pAi[j] - uAi[j] - qAi[j] + vAi[j];
            ZAr[j] = Ar - (c * Bi + s * Br);
            ZAi[j] = Ai + (c * Br - s * Bi);
        }
        {
            float Ar = pBr[j] + uBr[j] + qBr[j] + vBr[j];
            float Ai = pBi[j] + uBi[j] - qBi[j] - vBi[j];
            float Br = pBr[j] - uBr[j] + qBr[j] - vBr[j];
            float Bi = pBi[j] - uBi[j] - qBi[j] + vBi[j];
            ZBr[j] = Ar - (c * Bi + s * Br);
            ZBi[j] = Ai + (c * Br - s * Bi);
        }
    }

    // ---- in-register 8-pt inverse DIF (both rows) ----
    dif8(ZAr, ZAi);
    dif8(ZBr, ZBi);

    // ---- per-lane twiddle e^{+2pi i * lane * m2 / 512}, shared angles ----
    #pragma unroll
    for (int r = 1; r < 8; ++r) {
        float ang = 1.2271846303085129e-2f * (float)(lane * BR3[r]); // 2pi/512*lane*m2
        float s, c;
        __sincosf(ang, &s, &c);
        float xr = ZAr[r], xi = ZAi[r];
        ZAr[r] = xr * c - xi * s;
        ZAi[r] = xr * s + xi * c;
        xr = ZBr[r]; xi = ZBi[r];
        ZBr[r] = xr * c - xi * s;
        ZBi[r] = xr * s + xi * c;
    }

    // ---- 64-pt cross-lane inverse DFT, radix-2 DIF; stage twiddle shared ----
    #pragma unroll
    for (int st = 0; st < 6; ++st) {
        const int h   = 32 >> st;
        const bool hi = (lane & h) != 0;
        const float sgn = hi ? -1.0f : 1.0f;
        if (h > 1) {
            const int j = lane & (h - 1);
            float ang = hi ? (3.14159265358979323846f / (float)h) * (float)j : 0.0f;
            float ws, wc;
            __sincosf(ang, &ws, &wc);
            #pragma unroll
            for (int r = 0; r < 8; ++r) {
                float prA = __shfl_xor(ZAr[r], h);
                float piA = __shfl_xor(ZAi[r], h);
                float prB = __shfl_xor(ZBr[r], h);
                float piB = __shfl_xor(ZBi[r], h);
                float t1 = fmaf(sgn, ZAr[r], prA);
                float t2 = fmaf(sgn, ZAi[r], piA);
                ZAr[r] = t1 * wc - t2 * ws;
                ZAi[r] = t1 * ws + t2 * wc;
                t1 = fmaf(sgn, ZBr[r], prB);
                t2 = fmaf(sgn, ZBi[r], piB);
                ZBr[r] = t1 * wc - t2 * ws;
                ZBi[r] = t1 * ws + t2 * wc;
            }
        } else {
            #pragma unroll
            for (int r = 0; r < 8; ++r) {
                float prA = __shfl_xor(ZAr[r], 1);
                float piA = __shfl_xor(ZAi[r], 1);
                float prB = __shfl_xor(ZBr[r], 1);
                float piB = __shfl_xor(ZBi[r], 1);
                ZAr[r] = fmaf(sgn, ZAr[r], prA);
                ZAi[r] = fmaf(sgn, ZAi[r], piA);
                ZBr[r] = fmaf(sgn, ZBr[r], prB);
                ZBi[r] = fmaf(sgn, ZBi[r], piB);
            }
        }
    }

    // ---- unpack + scale: reg r holds w[m], m = BR3[r] + 8*br6(lane);
    //      y[2m] = Re*SC, y[2m+1] = Im*SC, SC = 1/2048 ----
    const float SC = 4.8828125e-4f;
    float valsA[16], valsB[16];
    #pragma unroll
    for (int r = 0; r < 8; ++r) {
        valsA[2 * BR3[r]]     = ZAr[r] * SC;
        valsA[2 * BR3[r] + 1] = ZAi[r] * SC;
        valsB[2 * BR3[r]]     = ZBr[r] * SC;
        valsB[2 * BR3[r] + 1] = ZBi[r] * SC;
    }

    float vmin = INFINITY, vmax = -INFINITY;
    #pragma unroll
    for (int i = 0; i < 16; ++i) {
        vmin = fminf(vmin, fminf(valsA[i], valsB[i]));
        vmax = fmaxf(vmax, fmaxf(valsA[i], valsB[i]));
    }

    // contiguous 16-float store per lane per row (4x float4 each)
    {
        float* obase = out + (size_t)rowA * FFT_N + 16 * br6(lane);
        #pragma unroll
        for (int q = 0; q < 4; ++q)
            *reinterpret_cast<float4*>(obase + 4 * q) =
                make_float4(valsA[4*q], valsA[4*q+1], valsA[4*q+2], valsA[4*q+3]);
    }
    {
        float* obase = out + (size_t)rowB * FFT_N + 16 * br6(lane);
        #pragma unroll
        for (int q = 0; q < 4; ++q)
            *reinterpret_cast<float4*>(obase + 4 * q) =
                make_float4(valsB[4*q], valsB[4*q+1], valsB[4*q+2], valsB[4*q+3]);
    }

    // ---- min/max: wave butterfly, cross-wave via LDS, one write per block ----
    #pragma unroll
    for (int off = 32; off >= 1; off >>= 1) {
        vmin = fminf(vmin, __shfl_xor(vmin, off));
        vmax = fmaxf(vmax, __shfl_xor(vmax, off));
    }
    __shared__ float smn[4], smx[4];
    if ((t & 63) == 0) { smn[wid] = vmin; smx[wid] = vmax; }
    __syncthreads();
    if (t == 0) {
        float mn = fminf(fminf(smn[0], smn[1]), fminf(smn[2], smn[3]));
        float mx = fmaxf(fmaxf(smx[0], smx[1]), fmaxf(smx[2], smx[3]));
        if (USE_ATOMIC) {
            atomicMin(&mm[0], f2key(mn));
            atomicMax(&mm[1], f2key(mx));
        } else {
            partials[2 * blockIdx.x]     = mn;
            partials[2 * blockIdx.x + 1] = mx;
        }
    }
}

// normalize with built-in reduction of the 2048 block partials (L2-hot, ~16 KB)
__global__ __launch_bounds__(256) void normalize_r(float* __restrict__ out,
                                                   const float* __restrict__ partials,
                                                   int n4) {
    float mn = INFINITY, mx = -INFINITY;
    #pragma unroll
    for (int it = 0; it < NBLK2 / 256; ++it) {
        float2 v = reinterpret_cast<const float2*>(partials)[threadIdx.x + it * 256];
        mn = fminf(mn, v.x);
        mx = fmaxf(mx, v.y);
    }
    #pragma unroll
    for (int off = 32; off >= 1; off >>= 1) {
        mn = fminf(mn, __shfl_xor(mn, off));
        mx = fmaxf(mx, __shfl_xor(mx, off));
    }
    __shared__ float smn[4], smx[4], bmm[2];
    const int wid = threadIdx.x >> 6;
    if ((threadIdx.x & 63) == 0) { smn[wid] = mn; smx[wid] = mx; }
    __syncthreads();
    if (threadIdx.x == 0) {
        bmm[0] = fminf(fminf(smn[0], smn[1]), fminf(smn[2], smn[3]));
        bmm[1] = fmaxf(fmaxf(smx[0], smx[1]), fmaxf(smx[2], smx[3]));
    }
    __syncthreads();
    const float MN  = bmm[0];
    const float INV = 1.0f / (bmm[1] - MN);

    float4n* o4 = reinterpret_cast<float4n*>(out);
    for (int i = blockIdx.x * blockDim.x + threadIdx.x; i < n4;
         i += gridDim.x * blockDim.x) {
        float4n v = o4[i];
        v.x = (v.x - MN) * INV;
        v.y = (v.y - MN) * INV;
        v.z = (v.z - MN) * INV;
        v.w = (v.w - MN) * INV;
        __builtin_nontemporal_store(v, &o4[i]);
    }
}

template <bool FROM_KEYS>
__global__ __launch_bounds__(256) void normalize_k(float* __restrict__ out,
                                                   const void* __restrict__ mmv,
                                                   int n4) {
    float mn, mx;
    if (FROM_KEYS) {
        const unsigned int* mm = (const unsigned int*)mmv;
        mn = key2f(mm[0]); mx = key2f(mm[1]);
    } else {
        const float* mm = (const float*)mmv;
        mn = mm[0]; mx = mm[1];
    }
    const float inv = 1.0f / (mx - mn);
    float4* o4 = reinterpret_cast<float4*>(out);
    for (int i = blockIdx.x * blockDim.x + threadIdx.x; i < n4;
         i += gridDim.x * blockDim.x) {
        float4 v = o4[i];
        v.x = (v.x - mn) * inv;
        v.y = (v.y - mn) * inv;
        v.z = (v.z - mn) * inv;
        v.w = (v.w - mn) * inv;
        o4[i] = v;
    }
}

extern "C" void kernel_launch(void* const* d_in, const int* in_sizes, int n_in,
                              void* d_out, int out_size, void* d_ws, size_t ws_size,
                              hipStream_t stream) {
    const float* x = (const float*)d_in[0];
    float* out = (float*)d_out;
    const int n4 = out_size / 4;

    if (ws_size >= (size_t)(2 * NBLK2) * sizeof(float)) {
        float* partials = (float*)d_ws;
        hipLaunchKernelGGL((zifft_rows2<false>), dim3(NBLK2), dim3(256), 0, stream,
                           x, out, partials, nullptr);
        hipLaunchKernelGGL(normalize_r, dim3(2048), dim3(256), 0, stream,
                           out, partials, n4);
    } else {
        unsigned int* mm = (unsigned int*)d_ws;
        hipLaunchKernelGGL(init_mm, dim3(1), dim3(1), 0, stream, mm);
        hipLaunchKernelGGL((zifft_rows2<true>), dim3(NBLK2), dim3(256), 0, stream,
                           x, out, nullptr, mm);
        hipLaunchKernelGGL((normalize_k<true>), dim3(2048), dim3(256), 0, stream,
                           out, (const void*)mm, n4);
    }
}

// Round 9
// 62.520 us; speedup vs baseline: 1.9603x; 1.9603x over previous
//
#include <hip/hip_runtime.h>

#define FFT_N 1024
#define NBLK 4096       // 4 waves/block, 1 row/wave -> 16384 rows

typedef float float4n __attribute__((ext_vector_type(4)));

__device__ __forceinline__ int br6(int x) { return (int)(__brev((unsigned)x) >> 26); }

__device__ __forceinline__ unsigned int f2key(float f) {
    unsigned int u = __float_as_uint(f);
    return (u & 0x80000000u) ? ~u : (u | 0x80000000u);
}
__device__ __forceinline__ float key2f(unsigned int k) {
    unsigned int u = (k & 0x80000000u) ? (k & 0x7FFFFFFFu) : ~k;
    return __uint_as_float(u);
}

__global__ void init_mm(unsigned int* mm) {
    mm[0] = 0xFFFFFFFFu;
    mm[1] = 0u;
}

// in-register 8-pt inverse DIF over reg index (natural in, bit-rev out)
__device__ __forceinline__ void dif8(float* Zr, float* Zi) {
    const float R = 0.70710678118654752f;
    float tr, ti;
    tr = Zr[0]-Zr[4]; ti = Zi[0]-Zi[4]; Zr[0]+=Zr[4]; Zi[0]+=Zi[4]; Zr[4]=tr;        Zi[4]=ti;
    tr = Zr[1]-Zr[5]; ti = Zi[1]-Zi[5]; Zr[1]+=Zr[5]; Zi[1]+=Zi[5]; Zr[5]=R*(tr-ti); Zi[5]=R*(tr+ti);
    tr = Zr[2]-Zr[6]; ti = Zi[2]-Zi[6]; Zr[2]+=Zr[6]; Zi[2]+=Zi[6]; Zr[6]=-ti;       Zi[6]=tr;
    tr = Zr[3]-Zr[7]; ti = Zi[3]-Zi[7]; Zr[3]+=Zr[7]; Zi[3]+=Zi[7]; Zr[7]=-R*(tr+ti);Zi[7]=R*(tr-ti);
    tr = Zr[0]-Zr[2]; ti = Zi[0]-Zi[2]; Zr[0]+=Zr[2]; Zi[0]+=Zi[2]; Zr[2]=tr;  Zi[2]=ti;
    tr = Zr[1]-Zr[3]; ti = Zi[1]-Zi[3]; Zr[1]+=Zr[3]; Zi[1]+=Zi[3]; Zr[3]=-ti; Zi[3]=tr;
    tr = Zr[4]-Zr[6]; ti = Zi[4]-Zi[6]; Zr[4]+=Zr[6]; Zi[4]+=Zi[6]; Zr[6]=tr;  Zi[6]=ti;
    tr = Zr[5]-Zr[7]; ti = Zi[5]-Zi[7]; Zr[5]+=Zr[7]; Zi[5]+=Zi[7]; Zr[7]=-ti; Zi[7]=tr;
    tr = Zr[0]-Zr[1]; ti = Zi[0]-Zi[1]; Zr[0]+=Zr[1]; Zi[0]+=Zi[1]; Zr[1]=tr; Zi[1]=ti;
    tr = Zr[2]-Zr[3]; ti = Zi[2]-Zi[3]; Zr[2]+=Zr[3]; Zi[2]+=Zi[3]; Zr[3]=tr; Zi[3]=ti;
    tr = Zr[4]-Zr[5]; ti = Zi[4]-Zi[5]; Zr[4]+=Zr[5]; Zi[4]+=Zi[5]; Zr[5]=tr; Zi[5]=ti;
    tr = Zr[6]-Zr[7]; ti = Zi[6]-Zi[7]; Zr[6]+=Zr[7]; Zi[6]+=Zi[7]; Zr[7]=tr; Zi[7]=ti;
}

// One row per wave. k = 8*lane + j layout: contiguous vector loads,
// Hermitian mirrors fetched from sibling lanes via shuffle.
template <bool USE_ATOMIC>
__global__ __launch_bounds__(256, 4) void hifft_rows(const float* __restrict__ x,
                                                     float* __restrict__ out,
                                                     float* __restrict__ partials,
                                                     unsigned int* __restrict__ mm) {
    const int t    = threadIdx.x;
    const int lane = t & 63;
    const int wid  = t >> 6;
    const int row  = blockIdx.x * 4 + wid;    // 0 .. 16383
    const int b    = row >> 10;
    const int p    = row & 1023;
    const float* re = x + (((size_t)(b * 2)) * 1024 + p) * 1024;
    const float* im = re + (size_t)1024 * 1024;

    // ---- loads: u = c[8l .. 8l+7], pp = c[512+8l .. 512+8l+7]  (8x dwordx4) ----
    float ur[8], ui[8], pr[8], pi[8];
    {
        const float4n* a = (const float4n*)(re + 8 * lane);
        const float4n* bq = (const float4n*)(re + 512 + 8 * lane);
        const float4n* c4 = (const float4n*)(im + 8 * lane);
        const float4n* d4 = (const float4n*)(im + 512 + 8 * lane);
        float4n v0 = a[0], v1 = a[1], w0 = bq[0], w1 = bq[1];
        float4n y0 = c4[0], y1 = c4[1], z0 = d4[0], z1 = d4[1];
        ur[0]=v0.x; ur[1]=v0.y; ur[2]=v0.z; ur[3]=v0.w;
        ur[4]=v1.x; ur[5]=v1.y; ur[6]=v1.z; ur[7]=v1.w;
        pr[0]=w0.x; pr[1]=w0.y; pr[2]=w0.z; pr[3]=w0.w;
        pr[4]=w1.x; pr[5]=w1.y; pr[6]=w1.z; pr[7]=w1.w;
        ui[0]=y0.x; ui[1]=y0.y; ui[2]=y0.z; ui[3]=y0.w;
        ui[4]=y1.x; ui[5]=y1.y; ui[6]=y1.z; ui[7]=y1.w;
        pi[0]=z0.x; pi[1]=z0.y; pi[2]=z0.z; pi[3]=z0.w;
        pi[4]=z1.x; pi[5]=z1.y; pi[6]=z1.z; pi[7]=z1.w;
    }

    // ---- pack Z[k] = A + i*W^k*B with shuffle-sourced mirrors ----
    //   k = 8*lane + j; q = c[512-k], v = c[(1024-k) mod 1024]
    //   j>=1: q = xor63(u[8-j]), v = xor63(pp[8-j])
    //   j==0: q = shfl(u[0], 64-l) (l==0 -> own pp[0]); v = shfl(pp[0], 64-l) (l==0 -> own u[0])
    float Zr[8], Zi[8];
    {
        const int srcd = (64 - lane) & 63;
        float q_r = __shfl(ur[0], srcd), q_i = __shfl(ui[0], srcd);
        float v_r = __shfl(pr[0], srcd), v_i = __shfl(pi[0], srcd);
        if (lane == 0) { q_r = pr[0]; q_i = pi[0]; v_r = ur[0]; v_i = ui[0]; }
        float s, c;
        __sincosf(6.135923151542565e-3f * (float)(8 * lane), &s, &c);
        float Ar = pr[0] + ur[0] + q_r + v_r;
        float Ai = pi[0] + ui[0] - q_i - v_i;
        float Br = pr[0] - ur[0] + q_r - v_r;
        float Bi = pi[0] - ui[0] - q_i + v_i;
        Zr[0] = Ar - (c * Bi + s * Br);
        Zi[0] = Ai + (c * Br - s * Bi);
    }
    #pragma unroll
    for (int j = 1; j < 8; ++j) {
        float q_r = __shfl_xor(ur[8 - j], 63), q_i = __shfl_xor(ui[8 - j], 63);
        float v_r = __shfl_xor(pr[8 - j], 63), v_i = __shfl_xor(pi[8 - j], 63);
        float s, c;
        __sincosf(6.135923151542565e-3f * (float)(8 * lane + j), &s, &c);
        float Ar = pr[j] + ur[j] + q_r + v_r;
        float Ai = pi[j] + ui[j] - q_i - v_i;
        float Br = pr[j] - ur[j] + q_r - v_r;
        float Bi = pi[j] - ui[j] - q_i + v_i;
        Zr[j] = Ar - (c * Bi + s * Br);
        Zi[j] = Ai + (c * Br - s * Bi);
    }

    // ---- 64-pt cross-lane inverse DFT over lanes (radix-2 DIF, natural in,
    //      bit-rev out), applied to all 8 regs; stage twiddle shared ----
    #pragma unroll
    for (int st = 0; st < 6; ++st) {
        const int h   = 32 >> st;
        const bool hi = (lane & h) != 0;
        const float sgn = hi ? -1.0f : 1.0f;
        if (h > 1) {
            const int j = lane & (h - 1);
            float ang = hi ? (3.14159265358979323846f / (float)h) * (float)j : 0.0f;
            float ws, wc;
            __sincosf(ang, &ws, &wc);
            #pragma unroll
            for (int r = 0; r < 8; ++r) {
                float prt = __shfl_xor(Zr[r], h);
                float pit = __shfl_xor(Zi[r], h);
                float t1 = fmaf(sgn, Zr[r], prt);
                float t2 = fmaf(sgn, Zi[r], pit);
                Zr[r] = t1 * wc - t2 * ws;
                Zi[r] = t1 * ws + t2 * wc;
            }
        } else {
            #pragma unroll
            for (int r = 0; r < 8; ++r) {
                float prt = __shfl_xor(Zr[r], 1);
                float pit = __shfl_xor(Zi[r], 1);
                Zr[r] = fmaf(sgn, Zr[r], prt);
                Zi[r] = fmaf(sgn, Zi[r], pit);
            }
        }
    }

    // ---- per-lane twiddle e^{+2pi i * j * n1 / 512}, n1 = br6(lane) ----
    const int n1 = br6(lane);
    #pragma unroll
    for (int r = 1; r < 8; ++r) {
        float ang = 1.2271846303085129e-2f * (float)(r * n1);  // 2pi/512 * j*n1
        float s, c;
        __sincosf(ang, &s, &c);
        float xr = Zr[r], xi = Zi[r];
        Zr[r] = xr * c - xi * s;
        Zi[r] = xr * s + xi * c;
    }

    // ---- 8-pt inverse DFT over regs (bit-rev out: reg r -> n2 = BR3[r]) ----
    dif8(Zr, Zi);

    // ---- unpack + store: X[m], m = n1 + 64*n2; y[2m]=Re*SC, y[2m+1]=Im*SC ----
    constexpr int BR3_[8] = {0, 4, 2, 6, 1, 5, 3, 7};
    const float SC = 4.8828125e-4f;   // 1/2048
    float* orow = out + (size_t)row * FFT_N + 2 * n1;
    float vmin = INFINITY, vmax = -INFINITY;
    #pragma unroll
    for (int r = 0; r < 8; ++r) {
        float a = Zr[r] * SC;
        float bb = Zi[r] * SC;
        vmin = fminf(vmin, fminf(a, bb));
        vmax = fmaxf(vmax, fmaxf(a, bb));
        *reinterpret_cast<float2*>(orow + 128 * BR3_[r]) = make_float2(a, bb);
    }

    // ---- min/max: wave butterfly, cross-wave via LDS, one write per block ----
    #pragma unroll
    for (int off = 32; off >= 1; off >>= 1) {
        vmin = fminf(vmin, __shfl_xor(vmin, off));
        vmax = fmaxf(vmax, __shfl_xor(vmax, off));
    }
    __shared__ float smn[4], smx[4];
    if ((t & 63) == 0) { smn[wid] = vmin; smx[wid] = vmax; }
    __syncthreads();
    if (t == 0) {
        float mn = fminf(fminf(smn[0], smn[1]), fminf(smn[2], smn[3]));
        float mx = fmaxf(fmaxf(smx[0], smx[1]), fmaxf(smx[2], smx[3]));
        if (USE_ATOMIC) {
            atomicMin(&mm[0], f2key(mn));
            atomicMax(&mm[1], f2key(mx));
        } else {
            partials[2 * blockIdx.x]     = mn;
            partials[2 * blockIdx.x + 1] = mx;
        }
    }
}

// normalize with built-in reduction of the 4096 block partials (L2/L3-hot)
__global__ __launch_bounds__(256) void normalize_r(float* __restrict__ out,
                                                   const float* __restrict__ partials,
                                                   int n4) {
    float mn = INFINITY, mx = -INFINITY;
    #pragma unroll
    for (int it = 0; it < NBLK / 256; ++it) {
        float2 v = reinterpret_cast<const float2*>(partials)[threadIdx.x + it * 256];
        mn = fminf(mn, v.x);
        mx = fmaxf(mx, v.y);
    }
    #pragma unroll
    for (int off = 32; off >= 1; off >>= 1) {
        mn = fminf(mn, __shfl_xor(mn, off));
        mx = fmaxf(mx, __shfl_xor(mx, off));
    }
    __shared__ float smn[4], smx[4], bmm[2];
    const int wid = threadIdx.x >> 6;
    if ((threadIdx.x & 63) == 0) { smn[wid] = mn; smx[wid] = mx; }
    __syncthreads();
    if (threadIdx.x == 0) {
        bmm[0] = fminf(fminf(smn[0], smn[1]), fminf(smn[2], smn[3]));
        bmm[1] = fmaxf(fmaxf(smx[0], smx[1]), fmaxf(smx[2], smx[3]));
    }
    __syncthreads();
    const float MN  = bmm[0];
    const float INV = 1.0f / (bmm[1] - MN);

    float4n* o4 = reinterpret_cast<float4n*>(out);
    for (int i = blockIdx.x * blockDim.x + threadIdx.x; i < n4;
         i += gridDim.x * blockDim.x) {
        float4n v = o4[i];
        v.x = (v.x - MN) * INV;
        v.y = (v.y - MN) * INV;
        v.z = (v.z - MN) * INV;
        v.w = (v.w - MN) * INV;
        __builtin_nontemporal_store(v, &o4[i]);
    }
}

template <bool FROM_KEYS>
__global__ __launch_bounds__(256) void normalize_k(float* __restrict__ out,
                                                   const void* __restrict__ mmv,
                                                   int n4) {
    float mn, mx;
    if (FROM_KEYS) {
        const unsigned int* mm = (const unsigned int*)mmv;
        mn = key2f(mm[0]); mx = key2f(mm[1]);
    } else {
        const float* mm = (const float*)mmv;
        mn = mm[0]; mx = mm[1];
    }
    const float inv = 1.0f / (mx - mn);
    float4n* o4 = reinterpret_cast<float4n*>(out);
    for (int i = blockIdx.x * blockDim.x + threadIdx.x; i < n4;
         i += gridDim.x * blockDim.x) {
        float4n v = o4[i];
        v.x = (v.x - mn) * inv;
        v.y = (v.y - mn) * inv;
        v.z = (v.z - mn) * inv;
        v.w = (v.w - mn) * inv;
        o4[i] = v;
    }
}

extern "C" void kernel_launch(void* const* d_in, const int* in_sizes, int n_in,
                              void* d_out, int out_size, void* d_ws, size_t ws_size,
                              hipStream_t stream) {
    const float* x = (const float*)d_in[0];
    float* out = (float*)d_out;
    const int n4 = out_size / 4;

    if (ws_size >= (size_t)(2 * NBLK) * sizeof(float)) {
        float* partials = (float*)d_ws;
        hipLaunchKernelGGL((hifft_rows<false>), dim3(NBLK), dim3(256), 0, stream,
                           x, out, partials, nullptr);
        hipLaunchKernelGGL(normalize_r, dim3(2048), dim3(256), 0, stream,
                           out, partials, n4);
    } else {
        unsigned int* mm = (unsigned int*)d_ws;
        hipLaunchKernelGGL(init_mm, dim3(1), dim3(1), 0, stream, mm);
        hipLaunchKernelGGL((hifft_rows<true>), dim3(NBLK), dim3(256), 0, stream,
                           x, out, nullptr, mm);
        hipLaunchKernelGGL((normalize_k<true>), dim3(2048), dim3(256), 0, stream,
                           out, (const void*)mm, n4);
    }
}